// Round 8
// baseline (230.994 us; speedup 1.0000x reference)
//
#include <hip/hip_runtime.h>
#include <hip/hip_cooperative_groups.h>
#include <math.h>

namespace cg = cooperative_groups;

#define BATCH 64
#define NN 512
#define DD 128
#define SLOPE 0.2f

typedef unsigned short u16;
typedef short bf16x8 __attribute__((ext_vector_type(8)));
typedef u16 u16x4 __attribute__((ext_vector_type(4)));
typedef u16 u16x8 __attribute__((ext_vector_type(8)));
typedef float f32x4 __attribute__((ext_vector_type(4)));

static __device__ __forceinline__ u16 f2bf(float x) {   // round-to-nearest-even
    unsigned int u = __float_as_uint(x);
    return (u16)((u + 0x7fffu + ((u >> 16) & 1u)) >> 16);
}
static __device__ __forceinline__ float bf2f(u16 h) {
    return __uint_as_float(((unsigned int)h) << 16);
}
// async global->LDS DMA, 16B/lane; lds base must be wave-uniform (HW: lds+lane*16)
static __device__ __forceinline__ void gld16(const u16* g, u16* lds) {
    __builtin_amdgcn_global_load_lds(
        (const __attribute__((address_space(1))) unsigned int*)g,
        (__attribute__((address_space(3))) unsigned int*)lds, 16, 0, 0);
}

// ---------------------------------------------------------------------------
// Single cooperative kernel. 256 blocks x 512 threads = 1 block/CU.
// Block (b, sub):  phase 1: z=E@W (split-bf16 MFMA), Ebf/zT/el/er/colsum,
//                  phase 2: fused masked-GAT attention for 128 j (m97-style
//                  global_load_lds staging, 2 barriers/chunk).
// ---------------------------------------------------------------------------
__global__ __launch_bounds__(512, 2) void k_all(
    const float* __restrict__ E, const float* __restrict__ W,
    const float* __restrict__ al, const float* __restrict__ ar,
    const float* __restrict__ bias,
    u16* __restrict__ Ebf, u16* __restrict__ zT,
    float* __restrict__ el, float* __restrict__ er,
    float* __restrict__ cs4, float* __restrict__ out)
{
    int bid = blockIdx.x;
    int b = (bid & 7) * 8 + (bid >> 5);   // same XCD for all 4 sub-blocks of b
    int sub = (bid >> 3) & 3;
    int t = threadIdx.x;
    int w = t >> 6;
    int lane = t & 63;
    int l15 = lane & 15;
    int quad = lane >> 4;

    __shared__ float csr[16][128];        // 8 KB (phase 1)
    __shared__ float elp_s[128], erp_s[128];
    __shared__ u16 Ei[64 * DD];           // 16 KB (phase 2)
    __shared__ u16 zTile[DD * 64];        // 16 KB
    __shared__ u16 pT[8][16][72];         // 18 KB, +8 pad
    __shared__ float tred[2];

    // ========================== PHASE 1: z = E @ W ==========================
    {
        int rg = sub;                      // row group: 128 rows
        for (int i = t; i < 128; i += 512) { elp_s[i] = 0.f; erp_s[i] = 0.f; }

        // coalesced colsum pre-pass (warms L2 with this block's E slice)
        int c4 = t & 31, r0 = t >> 5;
        const float* Eb1 = E + ((size_t)b * NN + rg * 128) * DD;
        float cp0 = 0.f, cp1 = 0.f, cp2 = 0.f, cp3 = 0.f;
        #pragma unroll
        for (int k = 0; k < 8; ++k) {
            int row = r0 + k * 16;
            float4 v = *(const float4*)&Eb1[(size_t)row * DD + c4 * 4];
            cp0 += v.x; cp1 += v.y; cp2 += v.z; cp3 += v.w;
        }
        csr[r0][c4 * 4 + 0] = cp0;
        csr[r0][c4 * 4 + 1] = cp1;
        csr[r0][c4 * 4 + 2] = cp2;
        csr[r0][c4 * 4 + 3] = cp3;
        __syncthreads();
        if (t < 128) {
            float s = 0.f;
            #pragma unroll
            for (int g = 0; g < 16; ++g) s += csr[g][t];
            cs4[((size_t)rg * BATCH + b) * DD + t] = s;
            if (rg == 0) out[b * DD + t] = 0.f;
        }

        // W^T fragments gathered straight into registers, split hi/lo
        int ch = w & 1, sg = w >> 1;
        bf16x8 bh[4][4], bl[4][4];
        float a_l[4], a_r[4];
        #pragma unroll
        for (int c = 0; c < 4; ++c) {
            int n = (ch * 4 + c) * 16 + l15;
            #pragma unroll
            for (int ks = 0; ks < 4; ++ks) {
                u16x8 hv, lv;
                #pragma unroll
                for (int j = 0; j < 8; ++j) {
                    float v = W[(size_t)(ks * 32 + quad * 8 + j) * DD + n];
                    u16 h = f2bf(v);
                    hv[j] = h;
                    lv[j] = f2bf(v - bf2f(h));
                }
                bh[c][ks] = (bf16x8)hv;
                bl[c][ks] = (bf16x8)lv;
            }
            a_l[c] = al[n];
            a_r[c] = ar[n];
        }

        #pragma unroll
        for (int si = 0; si < 2; ++si) {
            int s = sg * 2 + si;           // strip 0..7 (16 rows)
            int row = rg * 128 + s * 16 + l15;
            const float* Er = E + ((size_t)b * NN + row) * DD;

            bf16x8 ah[4], alo[4];
            #pragma unroll
            for (int ks = 0; ks < 4; ++ks) {
                float4 v0 = *(const float4*)(Er + ks * 32 + quad * 8);
                float4 v1 = *(const float4*)(Er + ks * 32 + quad * 8 + 4);
                float vv[8] = {v0.x, v0.y, v0.z, v0.w, v1.x, v1.y, v1.z, v1.w};
                u16x8 hv, lv;
                #pragma unroll
                for (int j = 0; j < 8; ++j) {
                    u16 h = f2bf(vv[j]);
                    hv[j] = h;
                    lv[j] = f2bf(vv[j] - bf2f(h));
                }
                ah[ks] = (bf16x8)hv;
                alo[ks] = (bf16x8)lv;
                if (ch == 0)
                    *(u16x8*)&Ebf[((size_t)b * NN + row) * DD + ks * 32 + quad * 8] = hv;
            }

            f32x4 C[4];
            #pragma unroll
            for (int c = 0; c < 4; ++c) C[c] = (f32x4){0.f, 0.f, 0.f, 0.f};
            #pragma unroll
            for (int ks = 0; ks < 4; ++ks)
                #pragma unroll
                for (int c = 0; c < 4; ++c) {
                    C[c] = __builtin_amdgcn_mfma_f32_16x16x32_bf16(ah[ks],  bh[c][ks], C[c], 0, 0, 0);
                    C[c] = __builtin_amdgcn_mfma_f32_16x16x32_bf16(alo[ks], bh[c][ks], C[c], 0, 0, 0);
                    C[c] = __builtin_amdgcn_mfma_f32_16x16x32_bf16(ah[ks],  bl[c][ks], C[c], 0, 0, 0);
                }

            float elp[4] = {0.f, 0.f, 0.f, 0.f};
            float erp[4] = {0.f, 0.f, 0.f, 0.f};
            #pragma unroll
            for (int c = 0; c < 4; ++c) {
                u16x4 zp;
                #pragma unroll
                for (int r = 0; r < 4; ++r) {
                    zp[r] = f2bf(C[c][r]);
                    elp[r] += C[c][r] * a_l[c];
                    erp[r] += C[c][r] * a_r[c];
                }
                *(u16x4*)&zT[((size_t)b * DD + (ch * 4 + c) * 16 + l15) * NN
                             + rg * 128 + s * 16 + quad * 4] = zp;
            }
            #pragma unroll
            for (int r = 0; r < 4; ++r) {
                float vl = elp[r], vr = erp[r];
                #pragma unroll
                for (int off = 8; off > 0; off >>= 1) {
                    vl += __shfl_down(vl, off);
                    vr += __shfl_down(vr, off);
                }
                if (l15 == 0) {
                    atomicAdd(&elp_s[s * 16 + quad * 4 + r], vl);
                    atomicAdd(&erp_s[s * 16 + quad * 4 + r], vr);
                }
            }
        }
        __syncthreads();
        if (t < 128) {
            el[b * NN + rg * 128 + t] = elp_s[t];
            er[b * NN + rg * 128 + t] = erp_s[t];
        }
    }

    __threadfence();
    cg::this_grid().sync();

    // ===================== PHASE 2: masked GAT attention ====================
    {
        int j0 = sub * 128;
        int jb = j0 + w * 16;               // this wave's 16 j
        const u16* Eb = Ebf + (size_t)b * NN * DD;
        const u16* zTb = zT + (size_t)b * DD * NN;

        // thresh = ||colsum||^2 / N^2
        if (t < 128) {
            float cc = 0.f;
            #pragma unroll
            for (int rg = 0; rg < 4; ++rg)
                cc += cs4[((size_t)rg * BATCH + b) * DD + t];
            float v = cc * cc;
            #pragma unroll
            for (int off = 32; off > 0; off >>= 1) v += __shfl_down(v, off);
            if ((t & 63) == 0) tred[t >> 6] = v;
        }

        bf16x8 bEj[4];
        #pragma unroll
        for (int ks = 0; ks < 4; ++ks)
            bEj[ks] = *(const bf16x8*)(Eb + (size_t)(jb + l15) * DD + ks * 32 + quad * 8);
        float er_v = er[b * NN + jb + l15];

        f32x4 H[8];
        #pragma unroll
        for (int nt = 0; nt < 8; ++nt) H[nt] = (f32x4){0.f, 0.f, 0.f, 0.f};
        f32x4 CZ = (f32x4){0.f, 0.f, 0.f, 0.f};
        bf16x8 one8;
        #pragma unroll
        for (int j = 0; j < 8; ++j) one8[j] = (short)0x3F80;

        __syncthreads();
        float thr = (tred[0] + tred[1]) * (1.0f / ((float)NN * (float)NN));

        for (int c = 0; c < 8; ++c) {
            int i0 = c * 64;

            // stage Ei rows (wave: 8 rows) + zTile d-rows (wave: 16 rows)
            #pragma unroll
            for (int g = 0; g < 2; ++g) {
                const u16* gp = Eb + (size_t)(i0 + w * 8 + g * 4 + (lane >> 4)) * DD + (lane & 15) * 8;
                gld16(gp, &Ei[(w * 8 + g * 4) * DD]);
            }
            #pragma unroll
            for (int g = 0; g < 2; ++g) {
                const u16* gp = zTb + (size_t)(w * 16 + g * 8 + (lane >> 3)) * NN + i0 + (lane & 7) * 8;
                gld16(gp, &zTile[(w * 16 + g * 8) * 64]);
            }
            __syncthreads();

            // scores for 4 i-subtiles -> mask -> exp -> wave-private pT
            #pragma unroll
            for (int it = 0; it < 4; ++it) {
                bf16x8 aE[4];
                #pragma unroll
                for (int ks = 0; ks < 4; ++ks)
                    aE[ks] = *(const bf16x8*)&Ei[(it * 16 + l15) * DD + ks * 32 + quad * 8];
                f32x4 S = (f32x4){0.f, 0.f, 0.f, 0.f};
                #pragma unroll
                for (int ks = 0; ks < 4; ++ks)
                    S = __builtin_amdgcn_mfma_f32_16x16x32_bf16(aE[ks], bEj[ks], S, 0, 0, 0);

                float4 el4 = *(const float4*)(el + b * NN + i0 + it * 16 + quad * 4);
                float elv[4] = {el4.x, el4.y, el4.z, el4.w};
                u16x4 pk;
                if (i0 + it * 16 == jb) {      // diagonal subtile: self-loops
                    #pragma unroll
                    for (int r = 0; r < 4; ++r) {
                        float x = elv[r] + er_v;
                        float lg = x > 0.f ? x : SLOPE * x;
                        bool keep = (S[r] > thr) || ((quad * 4 + r) == l15);
                        pk[r] = f2bf(keep ? __expf(lg) : 0.f);
                    }
                } else {
                    #pragma unroll
                    for (int r = 0; r < 4; ++r) {
                        float x = elv[r] + er_v;
                        float lg = x > 0.f ? x : SLOPE * x;
                        pk[r] = f2bf((S[r] > thr) ? __expf(lg) : 0.f);
                    }
                }
                *(u16x4*)&pT[w][l15][it * 16 + quad * 4] = pk;
            }

            // wave-private C->A transform (lgkmcnt only)
            bf16x8 ap[2];
            #pragma unroll
            for (int ks = 0; ks < 2; ++ks)
                ap[ks] = *(const bf16x8*)&pT[w][l15][ks * 32 + quad * 8];

            // aggregation + Z (ones-B)
            #pragma unroll
            for (int ks = 0; ks < 2; ++ks) {
                CZ = __builtin_amdgcn_mfma_f32_16x16x32_bf16(ap[ks], one8, CZ, 0, 0, 0);
                #pragma unroll
                for (int nt = 0; nt < 8; ++nt) {
                    bf16x8 bz = *(const bf16x8*)&zTile[(nt * 16 + l15) * 64 + ks * 32 + quad * 8];
                    H[nt] = __builtin_amdgcn_mfma_f32_16x16x32_bf16(ap[ks], bz, H[nt], 0, 0, 0);
                }
            }
            __syncthreads();
        }

        // epilogue: /Z, +bias, elu, sum this wave's 16 j, atomic out
        float zinv[4];
        #pragma unroll
        for (int r = 0; r < 4; ++r) zinv[r] = 1.0f / CZ[r];   // self-loop > 0

        #pragma unroll
        for (int nt = 0; nt < 8; ++nt) {
            float bsv = bias[nt * 16 + l15];
            float acc = 0.f;
            #pragma unroll
            for (int r = 0; r < 4; ++r) {
                float v = H[nt][r] * zinv[r] + bsv;
                v = v > 0.f ? v : (__expf(v) - 1.f);
                acc += v;
            }
            acc += __shfl_down(acc, 32);
            acc += __shfl_down(acc, 16);
            if (lane < 16) atomicAdd(&out[b * DD + nt * 16 + lane], acc * (1.0f / NN));
        }
    }
}

// ---------------------------------------------------------------------------
extern "C" void kernel_launch(void* const* d_in, const int* in_sizes, int n_in,
                              void* d_out, int out_size, void* d_ws, size_t ws_size,
                              hipStream_t stream) {
    const float* E    = (const float*)d_in[0];
    const float* W    = (const float*)d_in[1];
    const float* al   = (const float*)d_in[2];
    const float* ar   = (const float*)d_in[3];
    const float* bias = (const float*)d_in[4];
    float* out = (float*)d_out;

    u16* Ebf = (u16*)d_ws;                                     // 8 MB
    u16* zTb = Ebf + (size_t)BATCH * NN * DD;                  // 8 MB
    float* el  = (float*)(zTb + (size_t)BATCH * NN * DD);      // 128 KB
    float* er  = el + (size_t)BATCH * NN;                      // 128 KB
    float* cs4 = er + (size_t)BATCH * NN;                      // 128 KB

    void* args[] = {(void*)&E, (void*)&W, (void*)&al, (void*)&ar, (void*)&bias,
                    (void*)&Ebf, (void*)&zTb, (void*)&el, (void*)&er,
                    (void*)&cs4, (void*)&out};
    hipLaunchCooperativeKernel((const void*)k_all, dim3(256), dim3(512),
                               args, 0, stream);
}

// Round 9
// 121.153 us; speedup vs baseline: 1.9066x; 1.9066x over previous
//
#include <hip/hip_runtime.h>
#include <math.h>

#define BATCH 64
#define NN 512
#define DD 128
#define SLOPE 0.2f

typedef unsigned short u16;
typedef short bf16x8 __attribute__((ext_vector_type(8)));
typedef u16 u16x4 __attribute__((ext_vector_type(4)));
typedef u16 u16x8 __attribute__((ext_vector_type(8)));
typedef float f32x4 __attribute__((ext_vector_type(4)));

static __device__ __forceinline__ u16 f2bf(float x) {   // round-to-nearest-even
    unsigned int u = __float_as_uint(x);
    return (u16)((u + 0x7fffu + ((u >> 16) & 1u)) >> 16);
}
static __device__ __forceinline__ float bf2f(u16 h) {
    return __uint_as_float(((unsigned int)h) << 16);
}
// async global->LDS DMA, 16B/lane; lds base wave-uniform (HW: lds + lane*16)
static __device__ __forceinline__ void gld16(const u16* g, u16* lds) {
    __builtin_amdgcn_global_load_lds(
        (const __attribute__((address_space(1))) unsigned int*)g,
        (__attribute__((address_space(3))) unsigned int*)lds, 16, 0, 0);
}

// ---------------------------------------------------------------------------
// k_prep (129 blocks x 256): block 0: W^T bf16 hi/lo split;
// blocks 1..128: colsum half-partials + zero `out`.
// ---------------------------------------------------------------------------
__global__ __launch_bounds__(256) void k_prep(const float* __restrict__ W,
                                              const float* __restrict__ E,
                                              u16* __restrict__ WtHi,
                                              u16* __restrict__ WtLo,
                                              float* __restrict__ cs2,
                                              float* __restrict__ out) {
    __shared__ float csr[8][128];
    int t = threadIdx.x;
    if (blockIdx.x == 0) {
        int n = t & 127, half = t >> 7;
        #pragma unroll
        for (int g = 0; g < 8; ++g) {
            u16x8 hv, lv;
            #pragma unroll
            for (int j = 0; j < 8; ++j) {
                float v = W[(size_t)(half * 64 + g * 8 + j) * DD + n];
                u16 h = f2bf(v);
                hv[j] = h;
                lv[j] = f2bf(v - bf2f(h));
            }
            *(u16x8*)&WtHi[(size_t)n * DD + half * 64 + g * 8] = hv;
            *(u16x8*)&WtLo[(size_t)n * DD + half * 64 + g * 8] = lv;
        }
    } else {
        int b = (blockIdx.x - 1) >> 1;
        int half = (blockIdx.x - 1) & 1;
        int c4 = t & 31, r0 = t >> 5;
        const float* Eb = E + ((size_t)b * NN + half * 256) * DD;
        float cp0 = 0.f, cp1 = 0.f, cp2 = 0.f, cp3 = 0.f;
        for (int k = 0; k < 32; ++k) {
            int row = r0 + k * 8;
            float4 v = *(const float4*)&Eb[(size_t)row * DD + c4 * 4];
            cp0 += v.x; cp1 += v.y; cp2 += v.z; cp3 += v.w;
        }
        csr[r0][c4 * 4 + 0] = cp0;
        csr[r0][c4 * 4 + 1] = cp1;
        csr[r0][c4 * 4 + 2] = cp2;
        csr[r0][c4 * 4 + 3] = cp3;
        if (t < 64) out[b * DD + half * 64 + t] = 0.f;
        __syncthreads();
        if (t < 128) {
            float s = 0.f;
            #pragma unroll
            for (int g = 0; g < 8; ++g) s += csr[g][t];
            cs2[(size_t)half * BATCH * DD + b * DD + t] = s;
        }
    }
}

// ---------------------------------------------------------------------------
// k_z (512 blocks x 256, 2 blocks/CU): split-bf16 MFMA z = E@W.
// Block = (b, 64 rows). 4 waves = 2 strip-groups x 2 col-halves (4 nt each,
// persistent W frags). Emits Ebf, zT, el, er.
// ---------------------------------------------------------------------------
__global__ __launch_bounds__(256) void k_z(const float* __restrict__ E,
                                           const u16* __restrict__ WtHi,
                                           const u16* __restrict__ WtLo,
                                           const float* __restrict__ al,
                                           const float* __restrict__ ar,
                                           u16* __restrict__ Ebf,
                                           u16* __restrict__ zT,
                                           float* __restrict__ el,
                                           float* __restrict__ er) {
    int bid = blockIdx.x;
    int b = (bid & 7) * 8 + (bid >> 6);       // XCD swizzle
    int rg = (bid >> 3) & 7;                  // 64-row group
    int t = threadIdx.x;
    int w = t >> 6;
    int lane = t & 63;
    int l15 = lane & 15;
    int quad = lane >> 4;
    int sg = w >> 1;                          // strip-group 0..1
    int ch = w & 1;                           // col-half

    __shared__ float elp_s[64], erp_s[64];
    if (t < 64) { elp_s[t] = 0.f; erp_s[t] = 0.f; }
    __syncthreads();

    bf16x8 bh[4][4], bl[4][4];
    float a_l[4], a_r[4];
    #pragma unroll
    for (int c = 0; c < 4; ++c) {
        int nt = ch * 4 + c;
        #pragma unroll
        for (int ks = 0; ks < 4; ++ks) {
            bh[c][ks] = *(const bf16x8*)(WtHi + (size_t)(nt * 16 + l15) * DD + ks * 32 + quad * 8);
            bl[c][ks] = *(const bf16x8*)(WtLo + (size_t)(nt * 16 + l15) * DD + ks * 32 + quad * 8);
        }
        a_l[c] = al[nt * 16 + l15];
        a_r[c] = ar[nt * 16 + l15];
    }

    #pragma unroll
    for (int si = 0; si < 2; ++si) {
        int s = sg * 2 + si;                  // strip 0..3 (16 rows)
        int row = rg * 64 + s * 16 + l15;
        const float* Er = E + ((size_t)b * NN + row) * DD;

        bf16x8 ah[4], alo[4];
        #pragma unroll
        for (int ks = 0; ks < 4; ++ks) {
            float4 v0 = *(const float4*)(Er + ks * 32 + quad * 8);
            float4 v1 = *(const float4*)(Er + ks * 32 + quad * 8 + 4);
            float vv[8] = {v0.x, v0.y, v0.z, v0.w, v1.x, v1.y, v1.z, v1.w};
            u16x8 hv, lv;
            #pragma unroll
            for (int j = 0; j < 8; ++j) {
                u16 h = f2bf(vv[j]);
                hv[j] = h;
                lv[j] = f2bf(vv[j] - bf2f(h));
            }
            ah[ks] = (bf16x8)hv;
            alo[ks] = (bf16x8)lv;
            if (ch == 0)
                *(u16x8*)&Ebf[((size_t)b * NN + row) * DD + ks * 32 + quad * 8] = hv;
        }

        f32x4 C[4];
        #pragma unroll
        for (int c = 0; c < 4; ++c) C[c] = (f32x4){0.f, 0.f, 0.f, 0.f};
        #pragma unroll
        for (int ks = 0; ks < 4; ++ks)
            #pragma unroll
            for (int c = 0; c < 4; ++c) {
                C[c] = __builtin_amdgcn_mfma_f32_16x16x32_bf16(ah[ks],  bh[c][ks], C[c], 0, 0, 0);
                C[c] = __builtin_amdgcn_mfma_f32_16x16x32_bf16(alo[ks], bh[c][ks], C[c], 0, 0, 0);
                C[c] = __builtin_amdgcn_mfma_f32_16x16x32_bf16(ah[ks],  bl[c][ks], C[c], 0, 0, 0);
            }

        float elp[4] = {0.f, 0.f, 0.f, 0.f};
        float erp[4] = {0.f, 0.f, 0.f, 0.f};
        #pragma unroll
        for (int c = 0; c < 4; ++c) {
            u16x4 zp;
            #pragma unroll
            for (int r = 0; r < 4; ++r) {
                zp[r] = f2bf(C[c][r]);
                elp[r] += C[c][r] * a_l[c];
                erp[r] += C[c][r] * a_r[c];
            }
            *(u16x4*)&zT[((size_t)b * DD + (ch * 4 + c) * 16 + l15) * NN
                         + rg * 64 + s * 16 + quad * 4] = zp;
        }
        #pragma unroll
        for (int r = 0; r < 4; ++r) {
            float vl = elp[r], vr = erp[r];
            #pragma unroll
            for (int off = 8; off > 0; off >>= 1) {
                vl += __shfl_down(vl, off);
                vr += __shfl_down(vr, off);
            }
            if (l15 == 0) {
                atomicAdd(&elp_s[s * 16 + quad * 4 + r], vl);
                atomicAdd(&erp_s[s * 16 + quad * 4 + r], vr);
            }
        }
    }
    __syncthreads();
    if (t < 64) {
        el[b * NN + rg * 64 + t] = elp_s[t];
        er[b * NN + rg * 64 + t] = erp_s[t];
    }
}

// ---------------------------------------------------------------------------
// k_main (512 blocks x 256, 2 blocks/CU): m97-style fused attention with
// XOR-swizzled LDS tiles (conflict-free fragment reads).
// Block = (b, 64 j); wave w owns j rows [j0+16w, +16). 2 barriers/chunk.
//   Ei  layout: LDS[row][pcb] = G[row][pcb ^ (row&7)], pcb = 16B colblock 0..15
//   zT  layout: LDS[d][pcb]  = G[d][pcb ^ (d&7)],      pcb = 16B colblock 0..7
// ---------------------------------------------------------------------------
__global__ __launch_bounds__(256, 3) void k_main(const u16* __restrict__ Ebf,
                                                 const u16* __restrict__ zT,
                                                 const float* __restrict__ el,
                                                 const float* __restrict__ er,
                                                 const float* __restrict__ cs2,
                                                 const float* __restrict__ bias,
                                                 float* __restrict__ out) {
    int bid = blockIdx.x;
    int b = (bid & 7) * 8 + (bid >> 6);       // XCD swizzle (8 blocks/batch)
    int j0 = ((bid >> 3) & 7) * 64;
    int t = threadIdx.x;
    int w = t >> 6;
    int lane = t & 63;
    int l15 = lane & 15;
    int quad = lane >> 4;
    int jb = j0 + w * 16;

    const u16* Eb = Ebf + (size_t)b * NN * DD;
    const u16* zTb = zT + (size_t)b * DD * NN;

    __shared__ u16 Ei[64 * DD];       // 64 rows x 256B, swizzled colblocks
    __shared__ u16 zTile[DD * 64];    // 128 rows x 128B, swizzled colblocks
    __shared__ u16 pT[4][16][72];     // wave-private P^T, +8 pad
    __shared__ float tred[2];

    if (t < 128) {
        float c = cs2[b * DD + t] + cs2[BATCH * DD + b * DD + t];
        float v = c * c;
        #pragma unroll
        for (int off = 32; off > 0; off >>= 1) v += __shfl_down(v, off);
        if ((t & 63) == 0) tred[t >> 6] = v;
    }

    // persistent Ej B-frags (this wave's 16 j)
    bf16x8 bEj[4];
    #pragma unroll
    for (int ks = 0; ks < 4; ++ks)
        bEj[ks] = *(const bf16x8*)(Eb + (size_t)(jb + l15) * DD + ks * 32 + quad * 8);
    float er_v = er[b * NN + jb + l15];

    f32x4 H[8];
    #pragma unroll
    for (int nt = 0; nt < 8; ++nt) H[nt] = (f32x4){0.f, 0.f, 0.f, 0.f};
    f32x4 CZ = (f32x4){0.f, 0.f, 0.f, 0.f};
    bf16x8 one8;
    #pragma unroll
    for (int j = 0; j < 8; ++j) one8[j] = (short)0x3F80;

    __syncthreads();
    float thr = (tred[0] + tred[1]) * (1.0f / ((float)NN * (float)NN));

    int eswz = l15 & 7;               // row-swizzle for fragment reads

    for (int c = 0; c < 8; ++c) {
        int i0 = c * 64;

        // ---- stage Ei: wave w rows 16w..16w+15; 4 gld16 x 4 rows.
        // lane -> row = base + (lane>>4), pcb = lane&15, src cb = pcb^(row&7)
        #pragma unroll
        for (int g = 0; g < 4; ++g) {
            int rloc = w * 16 + g * 4 + (lane >> 4);
            int pcb = lane & 15;
            const u16* gp = Eb + (size_t)(i0 + rloc) * DD + (pcb ^ (rloc & 7)) * 8;
            gld16(gp, &Ei[(w * 16 + g * 4) * DD]);
        }
        // ---- stage zTile: wave w d-rows 32w..32w+31; 4 gld16 x 8 rows.
        // lane -> row = base + (lane>>3), pcb = lane&7, src cb = pcb^(row&7)
        #pragma unroll
        for (int g = 0; g < 4; ++g) {
            int dloc = w * 32 + g * 8 + (lane >> 3);
            int pcb = lane & 7;
            const u16* gp = zTb + (size_t)dloc * NN + i0 + (pcb ^ (dloc & 7)) * 8;
            gld16(gp, &zTile[(w * 32 + g * 8) * 64]);
        }
        __syncthreads();   // drains DMA + all waves staged

        // ---- scores for 4 i-subtiles -> mask -> exp -> wave-private pT
        #pragma unroll
        for (int it = 0; it < 4; ++it) {
            bf16x8 aE[4];
            #pragma unroll
            for (int ks = 0; ks < 4; ++ks)
                aE[ks] = *(const bf16x8*)&Ei[(it * 16 + l15) * DD + ((ks * 4 + quad) ^ eswz) * 8];
            f32x4 S = (f32x4){0.f, 0.f, 0.f, 0.f};
            #pragma unroll
            for (int ks = 0; ks < 4; ++ks)
                S = __builtin_amdgcn_mfma_f32_16x16x32_bf16(aE[ks], bEj[ks], S, 0, 0, 0);

            float4 el4 = *(const float4*)(el + b * NN + i0 + it * 16 + quad * 4);
            float elv[4] = {el4.x, el4.y, el4.z, el4.w};
            u16x4 pk;
            if (i0 + it * 16 == jb) {          // diagonal subtile: self-loops
                #pragma unroll
                for (int r = 0; r < 4; ++r) {
                    float x = elv[r] + er_v;
                    float lg = x > 0.f ? x : SLOPE * x;
                    bool keep = (S[r] > thr) || ((quad * 4 + r) == l15);
                    pk[r] = f2bf(keep ? __expf(lg) : 0.f);
                }
            } else {
                #pragma unroll
                for (int r = 0; r < 4; ++r) {
                    float x = elv[r] + er_v;
                    float lg = x > 0.f ? x : SLOPE * x;
                    pk[r] = f2bf((S[r] > thr) ? __expf(lg) : 0.f);
                }
            }
            *(u16x4*)&pT[w][l15][it * 16 + quad * 4] = pk;
        }

        // ---- wave-private C->A transform (lgkmcnt only, no barrier)
        bf16x8 ap[2];
        #pragma unroll
        for (int ks = 0; ks < 2; ++ks)
            ap[ks] = *(const bf16x8*)&pT[w][l15][ks * 32 + quad * 8];

        // ---- aggregation + Z (ones-B); zTile B-frags swizzle-read
        #pragma unroll
        for (int ks = 0; ks < 2; ++ks) {
            CZ = __builtin_amdgcn_mfma_f32_16x16x32_bf16(ap[ks], one8, CZ, 0, 0, 0);
            #pragma unroll
            for (int nt = 0; nt < 8; ++nt) {
                bf16x8 bz = *(const bf16x8*)&zTile[(nt * 16 + l15) * 64 + ((ks * 4 + quad) ^ eswz) * 8];
                H[nt] = __builtin_amdgcn_mfma_f32_16x16x32_bf16(ap[ks], bz, H[nt], 0, 0, 0);
            }
        }
        __syncthreads();   // all waves done reading before next stage
    }

    // ---- epilogue: /Z, +bias, elu, sum this wave's 16 j, atomic out
    float zinv[4];
    #pragma unroll
    for (int r = 0; r < 4; ++r) zinv[r] = 1.0f / CZ[r];   // self-loop > 0

    #pragma unroll
    for (int nt = 0; nt < 8; ++nt) {
        float bsv = bias[nt * 16 + l15];
        float acc = 0.f;
        #pragma unroll
        for (int r = 0; r < 4; ++r) {
            float v = H[nt][r] * zinv[r] + bsv;
            v = v > 0.f ? v : (__expf(v) - 1.f);
            acc += v;
        }
        acc += __shfl_down(acc, 32);
        acc += __shfl_down(acc, 16);
        if (lane < 16) atomicAdd(&out[b * DD + nt * 16 + lane], acc * (1.0f / NN));
    }
}

// ---------------------------------------------------------------------------
extern "C" void kernel_launch(void* const* d_in, const int* in_sizes, int n_in,
                              void* d_out, int out_size, void* d_ws, size_t ws_size,
                              hipStream_t stream) {
    const float* E    = (const float*)d_in[0];
    const float* W    = (const float*)d_in[1];
    const float* al   = (const float*)d_in[2];
    const float* ar   = (const float*)d_in[3];
    const float* bias = (const float*)d_in[4];
    float* out = (float*)d_out;

    u16* Ebf = (u16*)d_ws;                                     // 8 MB
    u16* zTb = Ebf + (size_t)BATCH * NN * DD;                  // 8 MB
    u16* WtHi = zTb + (size_t)BATCH * NN * DD;                 // 32 KB
    u16* WtLo = WtHi + (size_t)DD * DD;                        // 32 KB
    float* el  = (float*)(WtLo + (size_t)DD * DD);             // 128 KB
    float* er  = el + (size_t)BATCH * NN;                      // 128 KB
    float* cs2 = er + (size_t)BATCH * NN;                      // 64 KB

    k_prep<<<dim3(129), dim3(256), 0, stream>>>(W, E, WtHi, WtLo, cs2, out);
    k_z<<<dim3(512), dim3(256), 0, stream>>>(E, WtHi, WtLo, al, ar, Ebf, zTb, el, er);
    k_main<<<dim3(512), dim3(256), 0, stream>>>(Ebf, zTb, el, er, cs2, bias, out);
}

// Round 10
// 121.145 us; speedup vs baseline: 1.9068x; 1.0001x over previous
//
#include <hip/hip_runtime.h>
#include <math.h>

#define BATCH 64
#define NN 512
#define DD 128
#define SLOPE 0.2f

typedef unsigned short u16;
typedef short bf16x8 __attribute__((ext_vector_type(8)));
typedef u16 u16x4 __attribute__((ext_vector_type(4)));
typedef u16 u16x8 __attribute__((ext_vector_type(8)));
typedef float f32x4 __attribute__((ext_vector_type(4)));

static __device__ __forceinline__ u16 f2bf(float x) {   // round-to-nearest-even
    unsigned int u = __float_as_uint(x);
    return (u16)((u + 0x7fffu + ((u >> 16) & 1u)) >> 16);
}
static __device__ __forceinline__ float bf2f(u16 h) {
    return __uint_as_float(((unsigned int)h) << 16);
}

// ---------------------------------------------------------------------------
// k_z (512 blocks x 256): split-bf16 MFMA z = E@W.
// W^T hi/lo fragments gathered in-register from W (L2-resident, no prep
// kernel). Also emits: Ebf (bf16 hi of E), zT [B][D][N], el, er,
// cs8 (per-64-row colsum partials for the thresh identity), zeros `out`.
// Block = (b, 64 rows); 4 waves = 2 strip-groups x 2 col-halves.
// ---------------------------------------------------------------------------
__global__ __launch_bounds__(256) void k_z(const float* __restrict__ E,
                                           const float* __restrict__ W,
                                           const float* __restrict__ al,
                                           const float* __restrict__ ar,
                                           u16* __restrict__ Ebf,
                                           u16* __restrict__ zT,
                                           float* __restrict__ el,
                                           float* __restrict__ er,
                                           float* __restrict__ cs8,
                                           float* __restrict__ out) {
    int bid = blockIdx.x;
    int b = (bid & 7) * 8 + (bid >> 6);       // XCD swizzle
    int rg = (bid >> 3) & 7;                  // 64-row group
    int t = threadIdx.x;
    int w = t >> 6;
    int lane = t & 63;
    int l15 = lane & 15;
    int quad = lane >> 4;
    int sg = w >> 1;                          // strip-group 0..1
    int ch = w & 1;                           // col-half

    __shared__ float elp_s[64], erp_s[64];
    __shared__ float csp[2][128];
    if (t < 64) { elp_s[t] = 0.f; erp_s[t] = 0.f; }
    if (rg == 0 && t < 128) out[b * DD + t] = 0.f;  // zero for k_main atomics
    __syncthreads();

    // ---- W^T frags in-register (hi/lo split), 4 nt per wave
    bf16x8 bh[4][4], bl[4][4];
    float a_l[4], a_r[4];
    #pragma unroll
    for (int c = 0; c < 4; ++c) {
        int n = (ch * 4 + c) * 16 + l15;
        #pragma unroll
        for (int ks = 0; ks < 4; ++ks) {
            u16x8 hv, lv;
            #pragma unroll
            for (int j = 0; j < 8; ++j) {
                float v = W[(size_t)(ks * 32 + quad * 8 + j) * DD + n];
                u16 h = f2bf(v);
                hv[j] = h;
                lv[j] = f2bf(v - bf2f(h));
            }
            bh[c][ks] = (bf16x8)hv;
            bl[c][ks] = (bf16x8)lv;
        }
        a_l[c] = al[n];
        a_r[c] = ar[n];
    }

    float cs_l[32];
    #pragma unroll
    for (int i = 0; i < 32; ++i) cs_l[i] = 0.f;

    #pragma unroll
    for (int si = 0; si < 2; ++si) {
        int s = sg * 2 + si;                  // strip 0..3 (16 rows)
        int row = rg * 64 + s * 16 + l15;
        const float* Er = E + ((size_t)b * NN + row) * DD;

        bf16x8 ah[4], alo[4];
        #pragma unroll
        for (int ks = 0; ks < 4; ++ks) {
            float4 v0 = *(const float4*)(Er + ks * 32 + quad * 8);
            float4 v1 = *(const float4*)(Er + ks * 32 + quad * 8 + 4);
            float vv[8] = {v0.x, v0.y, v0.z, v0.w, v1.x, v1.y, v1.z, v1.w};
            u16x8 hv, lv;
            #pragma unroll
            for (int j = 0; j < 8; ++j) {
                u16 h = f2bf(vv[j]);
                hv[j] = h;
                lv[j] = f2bf(vv[j] - bf2f(h));
                if (ch == 0) cs_l[ks * 8 + j] += vv[j];   // colsum partials
            }
            ah[ks] = (bf16x8)hv;
            alo[ks] = (bf16x8)lv;
            if (ch == 0)
                *(u16x8*)&Ebf[((size_t)b * NN + row) * DD + ks * 32 + quad * 8] = hv;
        }

        f32x4 C[4];
        #pragma unroll
        for (int c = 0; c < 4; ++c) C[c] = (f32x4){0.f, 0.f, 0.f, 0.f};
        #pragma unroll
        for (int ks = 0; ks < 4; ++ks)
            #pragma unroll
            for (int c = 0; c < 4; ++c) {
                C[c] = __builtin_amdgcn_mfma_f32_16x16x32_bf16(ah[ks],  bh[c][ks], C[c], 0, 0, 0);
                C[c] = __builtin_amdgcn_mfma_f32_16x16x32_bf16(alo[ks], bh[c][ks], C[c], 0, 0, 0);
                C[c] = __builtin_amdgcn_mfma_f32_16x16x32_bf16(ah[ks],  bl[c][ks], C[c], 0, 0, 0);
            }

        float elp[4] = {0.f, 0.f, 0.f, 0.f};
        float erp[4] = {0.f, 0.f, 0.f, 0.f};
        #pragma unroll
        for (int c = 0; c < 4; ++c) {
            u16x4 zp;
            #pragma unroll
            for (int r = 0; r < 4; ++r) {
                zp[r] = f2bf(C[c][r]);
                elp[r] += C[c][r] * a_l[c];
                erp[r] += C[c][r] * a_r[c];
            }
            *(u16x4*)&zT[((size_t)b * DD + (ch * 4 + c) * 16 + l15) * NN
                         + rg * 64 + s * 16 + quad * 4] = zp;
        }
        #pragma unroll
        for (int r = 0; r < 4; ++r) {
            float vl = elp[r], vr = erp[r];
            #pragma unroll
            for (int off = 8; off > 0; off >>= 1) {
                vl += __shfl_down(vl, off);
                vr += __shfl_down(vr, off);
            }
            if (l15 == 0) {
                atomicAdd(&elp_s[s * 16 + quad * 4 + r], vl);
                atomicAdd(&erp_s[s * 16 + quad * 4 + r], vr);
            }
        }
    }

    // ---- colsum reduce (ch==0 waves): over the 16 rows (l15 lanes)
    if (ch == 0) {
        #pragma unroll
        for (int ks = 0; ks < 4; ++ks)
            #pragma unroll
            for (int j = 0; j < 8; ++j) {
                float v = cs_l[ks * 8 + j];
                v += __shfl_down(v, 8);
                v += __shfl_down(v, 4);
                v += __shfl_down(v, 2);
                v += __shfl_down(v, 1);
                if (l15 == 0) csp[sg][ks * 32 + quad * 8 + j] = v;
            }
    }
    __syncthreads();
    if (t < 64) {
        el[b * NN + rg * 64 + t] = elp_s[t];
        er[b * NN + rg * 64 + t] = erp_s[t];
    }
    if (t < 128)
        cs8[((size_t)rg * BATCH + b) * DD + t] = csp[0][t] + csp[1][t];
}

// ---------------------------------------------------------------------------
// k_main (512 blocks x 256): fused masked-GAT attention, register-direct
// fragments. Block = (b, 64 j). Scores: wave w owns i-rows [i0+16w,+16) x
// all 64 j (Ej persistent in regs). Agg: wave w owns d [32w,+32) x all 64 j.
// Only pT (C->A transpose) goes through LDS; 2 barriers/chunk.
// ---------------------------------------------------------------------------
__global__ __launch_bounds__(256, 2) void k_main(const u16* __restrict__ Ebf,
                                                 const u16* __restrict__ zT,
                                                 const float* __restrict__ el,
                                                 const float* __restrict__ er,
                                                 const float* __restrict__ cs8,
                                                 const float* __restrict__ bias,
                                                 float* __restrict__ out) {
    int bid = blockIdx.x;
    int b = (bid & 7) * 8 + (bid >> 6);       // XCD swizzle (8 blocks/batch)
    int j0 = ((bid >> 3) & 7) * 64;
    int t = threadIdx.x;
    int w = t >> 6;
    int lane = t & 63;
    int l15 = lane & 15;
    int quad = lane >> 4;

    const u16* Eb = Ebf + (size_t)b * NN * DD;
    const u16* zTb = zT + (size_t)b * DD * NN;

    __shared__ u16 pT[64][72];        // P^T [j][i-local], +8 pad
    __shared__ float zs_part[4][64];
    __shared__ float zfin[64];
    __shared__ float tred[2];

    // thresh = ||colsum||^2 / N^2
    if (t < 128) {
        float cc = 0.f;
        #pragma unroll
        for (int rg = 0; rg < 8; ++rg)
            cc += cs8[((size_t)rg * BATCH + b) * DD + t];
        float v = cc * cc;
        #pragma unroll
        for (int off = 32; off > 0; off >>= 1) v += __shfl_down(v, off);
        if ((t & 63) == 0) tred[t >> 6] = v;
    }

    // persistent Ej B-frags: all 64 j of this block (4 tiles)
    bf16x8 bEj[4][4];
    #pragma unroll
    for (int jt = 0; jt < 4; ++jt)
        #pragma unroll
        for (int ks = 0; ks < 4; ++ks)
            bEj[jt][ks] = *(const bf16x8*)(Eb + (size_t)(j0 + jt * 16 + l15) * DD + ks * 32 + quad * 8);
    float er_v[4];
    #pragma unroll
    for (int jt = 0; jt < 4; ++jt) er_v[jt] = er[b * NN + j0 + jt * 16 + l15];
    float bsv[2] = { bias[(2 * w + 0) * 16 + l15], bias[(2 * w + 1) * 16 + l15] };

    f32x4 H[4][2];
    #pragma unroll
    for (int jt = 0; jt < 4; ++jt) {
        H[jt][0] = (f32x4){0.f, 0.f, 0.f, 0.f};
        H[jt][1] = (f32x4){0.f, 0.f, 0.f, 0.f};
    }
    float zp[4] = {0.f, 0.f, 0.f, 0.f};

    __syncthreads();
    float thr = (tred[0] + tred[1]) * (1.0f / ((float)NN * (float)NN));

    for (int c8 = 0; c8 < 8; ++c8) {
        int i0 = c8 * 64;

        // agg B-frags (consumed after barrier -> deep latency slack)
        bf16x8 bz[2][2];
        #pragma unroll
        for (int cc = 0; cc < 2; ++cc)
            #pragma unroll
            for (int ks = 0; ks < 2; ++ks)
                bz[cc][ks] = *(const bf16x8*)(zTb + (size_t)((2 * w + cc) * 16 + l15) * NN + i0 + ks * 32 + quad * 8);

        // score A-frags: this wave's 16 i rows
        bf16x8 aE[4];
        #pragma unroll
        for (int ks = 0; ks < 4; ++ks)
            aE[ks] = *(const bf16x8*)(Eb + (size_t)(i0 + w * 16 + l15) * DD + ks * 32 + quad * 8);
        float4 el4 = *(const float4*)(el + b * NN + i0 + w * 16 + quad * 4);

        // scores: 16 i x 64 j
        f32x4 S[4];
        #pragma unroll
        for (int jt = 0; jt < 4; ++jt) S[jt] = (f32x4){0.f, 0.f, 0.f, 0.f};
        #pragma unroll
        for (int ks = 0; ks < 4; ++ks)
            #pragma unroll
            for (int jt = 0; jt < 4; ++jt)
                S[jt] = __builtin_amdgcn_mfma_f32_16x16x32_bf16(aE[ks], bEj[jt][ks], S[jt], 0, 0, 0);

        // mask + max-free exp -> pT; Z partials in regs
        float elv[4] = {el4.x, el4.y, el4.z, el4.w};
        int ig_base = i0 + w * 16 + quad * 4;
        #pragma unroll
        for (int jt = 0; jt < 4; ++jt) {
            int jg = j0 + jt * 16 + l15;
            float erv = er_v[jt];
            float ls = 0.f;
            u16x4 pk;
            #pragma unroll
            for (int r = 0; r < 4; ++r) {
                float x = elv[r] + erv;
                float lg = x > 0.f ? x : SLOPE * x;
                bool keep = (S[jt][r] > thr) || (ig_base + r == jg);
                float pe = keep ? __expf(lg) : 0.f;
                u16 pb = f2bf(pe);
                pk[r] = pb;
                ls += bf2f(pb);
            }
            zp[jt] += ls;
            *(u16x4*)&pT[jt * 16 + l15][w * 16 + quad * 4] = pk;
        }
        __syncthreads();    // pT visible to all waves

        // agg: H[64 j][this wave's 32 d] += P . z
        #pragma unroll
        for (int jt = 0; jt < 4; ++jt) {
            bf16x8 ap[2];
            #pragma unroll
            for (int ks = 0; ks < 2; ++ks)
                ap[ks] = *(const bf16x8*)&pT[jt * 16 + l15][ks * 32 + quad * 8];
            #pragma unroll
            for (int ks = 0; ks < 2; ++ks)
                #pragma unroll
                for (int cc = 0; cc < 2; ++cc)
                    H[jt][cc] = __builtin_amdgcn_mfma_f32_16x16x32_bf16(ap[ks], bz[cc][ks], H[jt][cc], 0, 0, 0);
        }
        __syncthreads();    // done reading pT before next chunk overwrites
    }

    // ---- Z: reduce zp over quads (i-direction), then across waves via LDS
    #pragma unroll
    for (int jt = 0; jt < 4; ++jt) {
        float v = zp[jt];
        v += __shfl_down(v, 32);
        v += __shfl_down(v, 16);
        if (lane < 16) zs_part[w][jt * 16 + lane] = v;
    }
    __syncthreads();
    if (t < 64)
        zfin[t] = 1.0f / (zs_part[0][t] + zs_part[1][t] + zs_part[2][t] + zs_part[3][t]);
    __syncthreads();

    // ---- epilogue: /Z, +bias, elu, sum over 64 j, atomic out
    float acc[2] = {0.f, 0.f};
    #pragma unroll
    for (int jt = 0; jt < 4; ++jt) {
        float4 zi = *(const float4*)&zfin[jt * 16 + quad * 4];
        float ziv[4] = {zi.x, zi.y, zi.z, zi.w};
        #pragma unroll
        for (int cc = 0; cc < 2; ++cc)
            #pragma unroll
            for (int r = 0; r < 4; ++r) {
                float v = H[jt][cc][r] * ziv[r] + bsv[cc];
                v = v > 0.f ? v : (__expf(v) - 1.f);
                acc[cc] += v;
            }
    }
    #pragma unroll
    for (int cc = 0; cc < 2; ++cc) {
        float v = acc[cc];
        v += __shfl_down(v, 32);
        v += __shfl_down(v, 16);
        if (lane < 16)
            atomicAdd(&out[b * DD + (2 * w + cc) * 16 + lane], v * (1.0f / NN));
    }
}

// ---------------------------------------------------------------------------
extern "C" void kernel_launch(void* const* d_in, const int* in_sizes, int n_in,
                              void* d_out, int out_size, void* d_ws, size_t ws_size,
                              hipStream_t stream) {
    const float* E    = (const float*)d_in[0];
    const float* W    = (const float*)d_in[1];
    const float* al   = (const float*)d_in[2];
    const float* ar   = (const float*)d_in[3];
    const float* bias = (const float*)d_in[4];
    float* out = (float*)d_out;

    u16* Ebf = (u16*)d_ws;                                     // 8 MB
    u16* zTb = Ebf + (size_t)BATCH * NN * DD;                  // 8 MB
    float* el  = (float*)(zTb + (size_t)BATCH * NN * DD);      // 128 KB
    float* er  = el + (size_t)BATCH * NN;                      // 128 KB
    float* cs8 = er + (size_t)BATCH * NN;                      // 256 KB

    k_z<<<dim3(512), dim3(256), 0, stream>>>(E, W, al, ar, Ebf, zTb, el, er, cs8, out);
    k_main<<<dim3(512), dim3(256), 0, stream>>>(Ebf, zTb, el, er, cs8, bias, out);
}

// Round 12
// 120.448 us; speedup vs baseline: 1.9178x; 1.0058x over previous
//
#include <hip/hip_runtime.h>
#include <math.h>

#define BATCH 64
#define NN 512
#define DD 128
#define SLOPE 0.2f

typedef unsigned short u16;
typedef short bf16x8 __attribute__((ext_vector_type(8)));
typedef u16 u16x4 __attribute__((ext_vector_type(4)));
typedef u16 u16x8 __attribute__((ext_vector_type(8)));
typedef float f32x4 __attribute__((ext_vector_type(4)));

static __device__ __forceinline__ u16 f2bf(float x) {   // round-to-nearest-even
    unsigned int u = __float_as_uint(x);
    return (u16)((u + 0x7fffu + ((u >> 16) & 1u)) >> 16);
}
static __device__ __forceinline__ float bf2f(u16 h) {
    return __uint_as_float(((unsigned int)h) << 16);
}

// ---------------------------------------------------------------------------
// k_z (512 blocks x 256): split-bf16 MFMA z = E@W.  (identical to R10)
// W^T hi/lo fragments gathered in-register. Emits Ebf, zT [B][D][N], el, er,
// cs8 (colsum partials for the thresh identity), zeros `out`.
// ---------------------------------------------------------------------------
__global__ __launch_bounds__(256) void k_z(const float* __restrict__ E,
                                           const float* __restrict__ W,
                                           const float* __restrict__ al,
                                           const float* __restrict__ ar,
                                           u16* __restrict__ Ebf,
                                           u16* __restrict__ zT,
                                           float* __restrict__ el,
                                           float* __restrict__ er,
                                           float* __restrict__ cs8,
                                           float* __restrict__ out) {
    int bid = blockIdx.x;
    int b = (bid & 7) * 8 + (bid >> 6);       // XCD swizzle
    int rg = (bid >> 3) & 7;                  // 64-row group
    int t = threadIdx.x;
    int w = t >> 6;
    int lane = t & 63;
    int l15 = lane & 15;
    int quad = lane >> 4;
    int sg = w >> 1;                          // strip-group 0..1
    int ch = w & 1;                           // col-half

    __shared__ float elp_s[64], erp_s[64];
    __shared__ float csp[2][128];
    if (t < 64) { elp_s[t] = 0.f; erp_s[t] = 0.f; }
    if (rg == 0 && t < 128) out[b * DD + t] = 0.f;  // zero for k_main atomics
    __syncthreads();

    // ---- W^T frags in-register (hi/lo split), 4 nt per wave
    bf16x8 bh[4][4], bl[4][4];
    float a_l[4], a_r[4];
    #pragma unroll
    for (int c = 0; c < 4; ++c) {
        int n = (ch * 4 + c) * 16 + l15;
        #pragma unroll
        for (int ks = 0; ks < 4; ++ks) {
            u16x8 hv, lv;
            #pragma unroll
            for (int j = 0; j < 8; ++j) {
                float v = W[(size_t)(ks * 32 + quad * 8 + j) * DD + n];
                u16 h = f2bf(v);
                hv[j] = h;
                lv[j] = f2bf(v - bf2f(h));
            }
            bh[c][ks] = (bf16x8)hv;
            bl[c][ks] = (bf16x8)lv;
        }
        a_l[c] = al[n];
        a_r[c] = ar[n];
    }

    float cs_l[32];
    #pragma unroll
    for (int i = 0; i < 32; ++i) cs_l[i] = 0.f;

    #pragma unroll
    for (int si = 0; si < 2; ++si) {
        int s = sg * 2 + si;                  // strip 0..3 (16 rows)
        int row = rg * 64 + s * 16 + l15;
        const float* Er = E + ((size_t)b * NN + row) * DD;

        bf16x8 ah[4], alo[4];
        #pragma unroll
        for (int ks = 0; ks < 4; ++ks) {
            float4 v0 = *(const float4*)(Er + ks * 32 + quad * 8);
            float4 v1 = *(const float4*)(Er + ks * 32 + quad * 8 + 4);
            float vv[8] = {v0.x, v0.y, v0.z, v0.w, v1.x, v1.y, v1.z, v1.w};
            u16x8 hv, lv;
            #pragma unroll
            for (int j = 0; j < 8; ++j) {
                u16 h = f2bf(vv[j]);
                hv[j] = h;
                lv[j] = f2bf(vv[j] - bf2f(h));
                if (ch == 0) cs_l[ks * 8 + j] += vv[j];   // colsum partials
            }
            ah[ks] = (bf16x8)hv;
            alo[ks] = (bf16x8)lv;
            if (ch == 0)
                *(u16x8*)&Ebf[((size_t)b * NN + row) * DD + ks * 32 + quad * 8] = hv;
        }

        f32x4 C[4];
        #pragma unroll
        for (int c = 0; c < 4; ++c) C[c] = (f32x4){0.f, 0.f, 0.f, 0.f};
        #pragma unroll
        for (int ks = 0; ks < 4; ++ks)
            #pragma unroll
            for (int c = 0; c < 4; ++c) {
                C[c] = __builtin_amdgcn_mfma_f32_16x16x32_bf16(ah[ks],  bh[c][ks], C[c], 0, 0, 0);
                C[c] = __builtin_amdgcn_mfma_f32_16x16x32_bf16(alo[ks], bh[c][ks], C[c], 0, 0, 0);
                C[c] = __builtin_amdgcn_mfma_f32_16x16x32_bf16(ah[ks],  bl[c][ks], C[c], 0, 0, 0);
            }

        float elp[4] = {0.f, 0.f, 0.f, 0.f};
        float erp[4] = {0.f, 0.f, 0.f, 0.f};
        #pragma unroll
        for (int c = 0; c < 4; ++c) {
            u16x4 zp;
            #pragma unroll
            for (int r = 0; r < 4; ++r) {
                zp[r] = f2bf(C[c][r]);
                elp[r] += C[c][r] * a_l[c];
                erp[r] += C[c][r] * a_r[c];
            }
            *(u16x4*)&zT[((size_t)b * DD + (ch * 4 + c) * 16 + l15) * NN
                         + rg * 64 + s * 16 + quad * 4] = zp;
        }
        #pragma unroll
        for (int r = 0; r < 4; ++r) {
            float vl = elp[r], vr = erp[r];
            #pragma unroll
            for (int off = 8; off > 0; off >>= 1) {
                vl += __shfl_down(vl, off);
                vr += __shfl_down(vr, off);
            }
            if (l15 == 0) {
                atomicAdd(&elp_s[s * 16 + quad * 4 + r], vl);
                atomicAdd(&erp_s[s * 16 + quad * 4 + r], vr);
            }
        }
    }

    // ---- colsum reduce (ch==0 waves)
    if (ch == 0) {
        #pragma unroll
        for (int ks = 0; ks < 4; ++ks)
            #pragma unroll
            for (int j = 0; j < 8; ++j) {
                float v = cs_l[ks * 8 + j];
                v += __shfl_down(v, 8);
                v += __shfl_down(v, 4);
                v += __shfl_down(v, 2);
                v += __shfl_down(v, 1);
                if (l15 == 0) csp[sg][ks * 32 + quad * 8 + j] = v;
            }
    }
    __syncthreads();
    if (t < 64) {
        el[b * NN + rg * 64 + t] = elp_s[t];
        er[b * NN + rg * 64 + t] = erp_s[t];
    }
    if (t < 128)
        cs8[((size_t)rg * BATCH + b) * DD + t] = csp[0][t] + csp[1][t];
}

// ---------------------------------------------------------------------------
// k_main (512 blocks x 256): fused masked-GAT attention, register-direct
// fragments, SOFTWARE-PIPELINED chunk loop (next chunk's aE/bz/el loads are
// issued right after barrier 1, in flight across agg MFMAs + barrier 2).
// Block = (b, 64 j). Scores: wave w owns i-rows [i0+16w,+16) x all 64 j.
// Agg: wave w owns d [32w,+32) x all 64 j. Only pT goes through LDS.
// ---------------------------------------------------------------------------
__global__ __launch_bounds__(256, 2) void k_main(const u16* __restrict__ Ebf,
                                                 const u16* __restrict__ zT,
                                                 const float* __restrict__ el,
                                                 const float* __restrict__ er,
                                                 const float* __restrict__ cs8,
                                                 const float* __restrict__ bias,
                                                 float* __restrict__ out) {
    int bid = blockIdx.x;
    int b = (bid & 7) * 8 + (bid >> 6);       // XCD swizzle (8 blocks/batch)
    int j0 = ((bid >> 3) & 7) * 64;
    int t = threadIdx.x;
    int w = t >> 6;
    int lane = t & 63;
    int l15 = lane & 15;
    int quad = lane >> 4;

    const u16* Eb = Ebf + (size_t)b * NN * DD;
    const u16* zTb = zT + (size_t)b * DD * NN;

    __shared__ u16 pT[64][72];        // P^T [j][i-local], +8 pad
    __shared__ float zs_part[4][64];
    __shared__ float zfin[64];
    __shared__ float tred[2];

    // thresh = ||colsum||^2 / N^2
    if (t < 128) {
        float cc = 0.f;
        #pragma unroll
        for (int rg = 0; rg < 8; ++rg)
            cc += cs8[((size_t)rg * BATCH + b) * DD + t];
        float v = cc * cc;
        #pragma unroll
        for (int off = 32; off > 0; off >>= 1) v += __shfl_down(v, off);
        if ((t & 63) == 0) tred[t >> 6] = v;
    }

    // persistent Ej B-frags: all 64 j of this block (4 tiles)
    bf16x8 bEj[4][4];
    #pragma unroll
    for (int jt = 0; jt < 4; ++jt)
        #pragma unroll
        for (int ks = 0; ks < 4; ++ks)
            bEj[jt][ks] = *(const bf16x8*)(Eb + (size_t)(j0 + jt * 16 + l15) * DD + ks * 32 + quad * 8);
    float er_v[4];
    #pragma unroll
    for (int jt = 0; jt < 4; ++jt) er_v[jt] = er[b * NN + j0 + jt * 16 + l15];
    float bsv[2] = { bias[(2 * w + 0) * 16 + l15], bias[(2 * w + 1) * 16 + l15] };

    f32x4 H[4][2];
    #pragma unroll
    for (int jt = 0; jt < 4; ++jt) {
        H[jt][0] = (f32x4){0.f, 0.f, 0.f, 0.f};
        H[jt][1] = (f32x4){0.f, 0.f, 0.f, 0.f};
    }
    float zp[4] = {0.f, 0.f, 0.f, 0.f};

    // chunk-load helpers (register-direct fragments)
    auto load_bz = [&](int i0, bf16x8 (&bzv)[2][2]) {
        #pragma unroll
        for (int cc = 0; cc < 2; ++cc)
            #pragma unroll
            for (int ks = 0; ks < 2; ++ks)
                bzv[cc][ks] = *(const bf16x8*)(zTb + (size_t)((2 * w + cc) * 16 + l15) * NN + i0 + ks * 32 + quad * 8);
    };
    auto load_aE = [&](int i0, bf16x8 (&aEv)[4]) {
        #pragma unroll
        for (int ks = 0; ks < 4; ++ks)
            aEv[ks] = *(const bf16x8*)(Eb + (size_t)(i0 + w * 16 + l15) * DD + ks * 32 + quad * 8);
    };

    // preload chunk 0
    bf16x8 bz[2][2], aE[4];
    float4 el4;
    load_bz(0, bz);
    load_aE(0, aE);
    el4 = *(const float4*)(el + b * NN + 0 + w * 16 + quad * 4);

    __syncthreads();
    float thr = (tred[0] + tred[1]) * (1.0f / ((float)NN * (float)NN));

    for (int c8 = 0; c8 < 8; ++c8) {
        int i0 = c8 * 64;
        int i0n = ((c8 + 1) & 7) * 64;        // wraps: last prefetch redundant

        // scores: 16 i x 64 j (current chunk's aE)
        f32x4 S[4];
        #pragma unroll
        for (int jt = 0; jt < 4; ++jt) S[jt] = (f32x4){0.f, 0.f, 0.f, 0.f};
        #pragma unroll
        for (int ks = 0; ks < 4; ++ks)
            #pragma unroll
            for (int jt = 0; jt < 4; ++jt)
                S[jt] = __builtin_amdgcn_mfma_f32_16x16x32_bf16(aE[ks], bEj[jt][ks], S[jt], 0, 0, 0);

        // mask + max-free exp -> pT; Z partials in regs
        float elv[4] = {el4.x, el4.y, el4.z, el4.w};
        int ig_base = i0 + w * 16 + quad * 4;
        #pragma unroll
        for (int jt = 0; jt < 4; ++jt) {
            int jg = j0 + jt * 16 + l15;
            float erv = er_v[jt];
            float ls = 0.f;
            u16x4 pk;
            #pragma unroll
            for (int r = 0; r < 4; ++r) {
                float x = elv[r] + erv;
                float lg = x > 0.f ? x : SLOPE * x;
                bool keep = (S[jt][r] > thr) || (ig_base + r == jg);
                float pe = keep ? __expf(lg) : 0.f;
                u16 pb = f2bf(pe);
                pk[r] = pb;
                ls += bf2f(pb);
            }
            zp[jt] += ls;
            *(u16x4*)&pT[jt * 16 + l15][w * 16 + quad * 4] = pk;
        }
        __syncthreads();    // barrier 1: pT visible to all waves

        // ---- prefetch next chunk (in flight across agg + barrier 2)
        bf16x8 bzN[2][2], aEN[4];
        float4 el4N;
        load_bz(i0n, bzN);
        load_aE(i0n, aEN);
        el4N = *(const float4*)(el + b * NN + i0n + w * 16 + quad * 4);

        // agg: H[64 j][this wave's 32 d] += P . z (current chunk's bz)
        #pragma unroll
        for (int jt = 0; jt < 4; ++jt) {
            bf16x8 ap[2];
            #pragma unroll
            for (int ks = 0; ks < 2; ++ks)
                ap[ks] = *(const bf16x8*)&pT[jt * 16 + l15][ks * 32 + quad * 8];
            #pragma unroll
            for (int ks = 0; ks < 2; ++ks)
                #pragma unroll
                for (int cc = 0; cc < 2; ++cc)
                    H[jt][cc] = __builtin_amdgcn_mfma_f32_16x16x32_bf16(ap[ks], bz[cc][ks], H[jt][cc], 0, 0, 0);
        }
        __syncthreads();    // barrier 2: done reading pT before next chunk

        // rotate pipeline registers
        #pragma unroll
        for (int cc = 0; cc < 2; ++cc)
            #pragma unroll
            for (int ks = 0; ks < 2; ++ks)
                bz[cc][ks] = bzN[cc][ks];
        #pragma unroll
        for (int ks = 0; ks < 4; ++ks) aE[ks] = aEN[ks];
        el4 = el4N;
    }

    // ---- Z: reduce zp over quads (i-direction), then across waves via LDS
    #pragma unroll
    for (int jt = 0; jt < 4; ++jt) {
        float v = zp[jt];
        v += __shfl_down(v, 32);
        v += __shfl_down(v, 16);
        if (lane < 16) zs_part[w][jt * 16 + lane] = v;
    }
    __syncthreads();
    if (t < 64)
        zfin[t] = 1.0f / (zs_part[0][t] + zs_part[1][t] + zs_part[2][t] + zs_part[3][t]);
    __syncthreads();

    // ---- epilogue: /Z, +bias, elu, sum over 64 j, atomic out
    float acc[2] = {0.f, 0.f};
    #pragma unroll
    for (int jt = 0; jt < 4; ++jt) {
        float4 zi = *(const float4*)&zfin[jt * 16 + quad * 4];
        float ziv[4] = {zi.x, zi.y, zi.z, zi.w};
        #pragma unroll
        for (int cc = 0; cc < 2; ++cc)
            #pragma unroll
            for (int r = 0; r < 4; ++r) {
                float v = H[jt][cc][r] * ziv[r] + bsv[cc];
                v = v > 0.f ? v : (__expf(v) - 1.f);
                acc[cc] += v;
            }
    }
    #pragma unroll
    for (int cc = 0; cc < 2; ++cc) {
        float v = acc[cc];
        v += __shfl_down(v, 32);
        v += __shfl_down(v, 16);
        if (lane < 16)
            atomicAdd(&out[b * DD + (2 * w + cc) * 16 + lane], v * (1.0f / NN));
    }
}

// ---------------------------------------------------------------------------
extern "C" void kernel_launch(void* const* d_in, const int* in_sizes, int n_in,
                              void* d_out, int out_size, void* d_ws, size_t ws_size,
                              hipStream_t stream) {
    const float* E    = (const float*)d_in[0];
    const float* W    = (const float*)d_in[1];
    const float* al   = (const float*)d_in[2];
    const float* ar   = (const float*)d_in[3];
    const float* bias = (const float*)d_in[4];
    float* out = (float*)d_out;

    u16* Ebf = (u16*)d_ws;                                     // 8 MB
    u16* zTb = Ebf + (size_t)BATCH * NN * DD;                  // 8 MB
    float* el  = (float*)(zTb + (size_t)BATCH * NN * DD);      // 128 KB
    float* er  = el + (size_t)BATCH * NN;                      // 128 KB
    float* cs8 = er + (size_t)BATCH * NN;                      // 256 KB

    k_z<<<dim3(512), dim3(256), 0, stream>>>(E, W, al, ar, Ebf, zTb, el, er, cs8, out);
    k_main<<<dim3(512), dim3(256), 0, stream>>>(Ebf, zTb, el, er, cs8, bias, out);
}